// Round 6
// baseline (111.291 us; speedup 1.0000x reference)
//
#include <hip/hip_runtime.h>
#include <hip/hip_fp16.h>

#define TAU 0.07f
#define MARGIN 0.2f
#define NSPEC 64
#define BB 8192
#define DD 256

// ---------------- ws layout (bytes) ----------------
//   0      float scalars[8] [0]=triSum [1]=infoSum [2]=n_valid [3]=n_valid_i [4]=done
//                                        (zeroed by kA block 0, then [2],[3] written)
//   64     int   counts[64]              (kA block 0)
//   320    int   offsets[64]             (kA block 0)
//   1024   float lseRow[8192]  32 KB     (zeroed by kA blocks 1-32; atomic kB)
//   33792  float lseCol[8192]  32 KB     (zeroed by kA blocks 1-32; atomic kB)
//   66560  float Ts[64][256]   64 KB     (zeroed by kA blocks 1-32; atomic kB)
//   132096 float T[256]        1 KB      (zeroed by kA blocks 1-32; atomic kB T-role)
//   133120 int   memberList[8192] 32 KB  (kA block 0)
#define WS_SCALARS   0
#define WS_COUNTS    64
#define WS_OFFSETS   320
#define WS_LSEROW    1024
#define WS_LSECOL    33792
#define WS_TS        66560
#define WS_T         132096
#define WS_MEMBER    133120
// zero region [1024, 133120) = 132096 B = 32 blocks x 4128 B (258 float4 each)

typedef _Float16 half8 __attribute__((ext_vector_type(8)));
typedef float float4v __attribute__((ext_vector_type(4)));
typedef unsigned int uint4v __attribute__((ext_vector_type(4)));

__device__ __forceinline__ uint4v pack8(float4 a, float4 b) {
  half8 h;
  h[0] = (_Float16)a.x; h[1] = (_Float16)a.y; h[2] = (_Float16)a.z; h[3] = (_Float16)a.w;
  h[4] = (_Float16)b.x; h[5] = (_Float16)b.y; h[6] = (_Float16)b.z; h[7] = (_Float16)b.w;
  return __builtin_bit_cast(uint4v, h);
}

__device__ __forceinline__ float dot4(float4 a, float4 b) {
  return a.x * b.x + a.y * b.y + a.z * b.z + a.w * b.w;
}

// ---- kA: block 0 = histogram/scan/scatter (+scalars zero);
//          blocks 1..32 = zero [1024,133120) (4128 B each, disjoint) ----
__global__ void kA(const int* __restrict__ ids, char* __restrict__ ws) {
  int bid = blockIdx.x, tid = threadIdx.x;
  if (bid == 0) {
    int* counts_g = (int*)(ws + WS_COUNTS);
    int* offsets_g = (int*)(ws + WS_OFFSETS);
    int* memberList = (int*)(ws + WS_MEMBER);
    float* scalars = (float*)(ws + WS_SCALARS);
    __shared__ int cnt[NSPEC];
    __shared__ int off[NSPEC];
    if (tid < 8) ((unsigned*)scalars)[tid] = 0u;
    if (tid < NSPEC) cnt[tid] = 0;
    __syncthreads();
    int myS[8], myP[8];
    #pragma unroll
    for (int r = 0; r < 8; ++r) {
      int i = r * 1024 + tid;
      int s = ids[i];
      myS[r] = s;
      myP[r] = atomicAdd(&cnt[s], 1);
    }
    __syncthreads();
    if (tid < NSPEC) {  // exactly wave 0
      int o = 0;
      for (int t = 0; t < NSPEC; ++t) o += (t < tid) ? cnt[t] : 0;
      off[tid] = o;
      offsets_g[tid] = o;
      int c = cnt[tid];
      counts_g[tid] = c;
      unsigned long long bv = __ballot(c >= 2);
      float nvi = (c >= 2 && c <= BB - 1) ? (float)c : 0.f;
      for (int o2 = 1; o2 < 64; o2 <<= 1) nvi += __shfl_xor(nvi, o2);
      if (tid == 0) {
        scalars[2] = (float)__popcll(bv);
        scalars[3] = nvi;
      }
    }
    __syncthreads();
    #pragma unroll
    for (int r = 0; r < 8; ++r) {
      int i = r * 1024 + tid;
      memberList[off[myS[r]] + myP[r]] = i;
    }
  } else {
    int b = bid - 1;  // 0..31
    if (tid < 258) {
      float4v z4 = {0.f, 0.f, 0.f, 0.f};
      *(float4v*)(ws + WS_LSEROW + b * 4128 + tid * 16) = z4;
    }
  }
}

// ---- kB: bid<512 = k5 MFMA-LSE (proven); 512..1023 = k2 Ts slices;
//          1024..1279 = T accumulation from tx (32 rows/block, overlapped) ----
__global__ void kB(const float* __restrict__ sp, const float* __restrict__ tx,
                   const int* __restrict__ counts, const int* __restrict__ offsets,
                   const int* __restrict__ memberList,
                   float* Ts, float* T, float* lseRow, float* lseCol) {
  __shared__ uint4v frag[1536];  // 24 KB (k5 role)
  __shared__ int idx[192];       // tile row indices: A rows [0,64), B rows [64,192)
  int bid = blockIdx.x;
  int tid = threadIdx.x;

  if (bid >= 1024) {
    // ---- T role: 256 blocks, each sums 32 rows of tx; 256 adds/address over kB ----
    int b = bid - 1024;
    int d = tid;
    const float* base = tx + (b * 32) * DD + d;
    float acc = 0.f;
    #pragma unroll 8
    for (int rr = 0; rr < 32; ++rr) acc += base[rr * DD];
    atomicAdd(&T[d], acc);
    return;
  }
  if (bid >= 512) {
    // ---- k2 role: per-species text sums Ts[s][d], batched-gather pipeline ----
    int v2 = bid - 512;
    int s = v2 & 63, r = v2 >> 6;
    int m = counts[s], g0 = offsets[s];
    int k0 = (m * r) >> 3, k1e = (m * (r + 1)) >> 3;
    if (k0 >= k1e) return;
    int d = tid;
    float acc = 0.f;
    int k = k0;
    for (; k + 4 <= k1e; k += 4) {
      int i0 = memberList[g0 + k];
      int i1 = memberList[g0 + k + 1];
      int i2 = memberList[g0 + k + 2];
      int i3 = memberList[g0 + k + 3];
      float a0 = tx[i0 * DD + d];
      float a1 = tx[i1 * DD + d];
      float a2 = tx[i2 * DD + d];
      float a3 = tx[i3 * DD + d];
      acc += a0 + a1 + a2 + a3;
    }
    for (; k < k1e; ++k) acc += tx[memberList[g0 + k] * DD + d];
    atomicAdd(&Ts[s * DD + d], acc);
    return;
  }

  // ---- k5 role: 64x128 masked sum-of-exp via MFMA f16, K=256 in 4 chunks ----
  int s = bid & 63;
  int m = counts[s];
  int g0 = offsets[s];
  int lane = tid & 63, wv = tid >> 6;
  int quad = lane >> 4, cl = lane & 15;
  int rt0 = (bid >> 6) & 3, ct0 = (bid >> 8) & 1;  // strides 4, 2

  for (int rt = rt0; rt * 64 < m; rt += 4) {
    for (int ct = ct0; ct * 128 < m; ct += 2) {
      // tile prologue: hoist member indices to LDS ONCE per tile
      __syncthreads();
      if (tid < 192) {
        int base = (tid < 64) ? (rt * 64 + tid) : (ct * 128 + (tid - 64));
        idx[tid] = (base < m) ? memberList[g0 + base] : -1;
      }
      __syncthreads();

      const float* srcB[6];
      bool val[6];
      int dst[6];
      float4 r0[6], r1[6];
      #pragma unroll
      for (int p = 0; p < 6; ++p) {
        int u = p * 256 + tid;
        int isB = u >= 512;
        int v = isB ? (u - 512) : u;
        int row = v >> 3, sub = v & 7;
        int ksl = sub >> 2, q = sub & 3;
        int ridx = idx[isB ? (64 + row) : row];
        val[p] = ridx >= 0;
        srcB[p] = (isB ? tx : sp) + (val[p] ? ridx : 0) * DD + ksl * 32 + q * 8;
        dst[p] = isB ? (512 + (ksl * 128 + row) * 4 + q)
                     : ((ksl * 64 + row) * 4 + q);
      }
      #pragma unroll
      for (int p = 0; p < 6; ++p) {
        r0[p] = *reinterpret_cast<const float4*>(srcB[p]);
        r1[p] = *reinterpret_cast<const float4*>(srcB[p] + 4);
      }

      float4v acc[8];
      #pragma unroll
      for (int cf = 0; cf < 8; ++cf) acc[cf] = (float4v){0.f, 0.f, 0.f, 0.f};

      for (int kc = 0; kc < 4; ++kc) {
        __syncthreads();
        uint4v z4 = (uint4v){0u, 0u, 0u, 0u};
        #pragma unroll
        for (int p = 0; p < 6; ++p)
          frag[dst[p]] = val[p] ? pack8(r0[p], r1[p]) : z4;
        __syncthreads();
        if (kc < 3) {
          #pragma unroll
          for (int p = 0; p < 6; ++p) {
            r0[p] = *reinterpret_cast<const float4*>(srcB[p] + (kc + 1) * 64);
            r1[p] = *reinterpret_cast<const float4*>(srcB[p] + (kc + 1) * 64 + 4);
          }
        }
        #pragma unroll
        for (int ksl = 0; ksl < 2; ++ksl) {
          half8 a = __builtin_bit_cast(half8, frag[(ksl * 64 + wv * 16 + cl) * 4 + quad]);
          #pragma unroll
          for (int cf = 0; cf < 8; ++cf) {
            half8 b = __builtin_bit_cast(half8, frag[512 + (ksl * 128 + cf * 16 + cl) * 4 + quad]);
            acc[cf] = __builtin_amdgcn_mfma_f32_16x16x32_f16(a, b, acc[cf], 0, 0, 0);
          }
        }
      }

      // epilogue: masked exp, row/col sums
      int riBase = rt * 64 + wv * 16 + quad * 4;
      float rowAcc[4] = {0.f, 0.f, 0.f, 0.f};
      #pragma unroll
      for (int cf = 0; cf < 8; ++cf) {
        int ci = ct * 128 + cf * 16 + cl;
        bool cv = ci < m;
        float colAcc = 0.f;
        #pragma unroll
        for (int reg = 0; reg < 4; ++reg) {
          bool rv = (riBase + reg) < m;
          float e = (rv && cv) ? __expf(acc[cf][reg] * (1.f / TAU)) : 0.f;
          rowAcc[reg] += e;
          colAcc += e;
        }
        colAcc += __shfl_xor(colAcc, 16);
        colAcc += __shfl_xor(colAcc, 32);
        if (quad == 0 && cv) atomicAdd(&lseCol[g0 + ci], colAcc);
      }
      #pragma unroll
      for (int reg = 0; reg < 4; ++reg) {
        float v = rowAcc[reg];
        v += __shfl_xor(v, 1);
        v += __shfl_xor(v, 2);
        v += __shfl_xor(v, 4);
        v += __shfl_xor(v, 8);
        if (cl == 0 && (riBase + reg) < m) atomicAdd(&lseRow[g0 + riBase + reg], v);
      }
    }
  }
}

// ---- kC: fused dots + CE + triplet + done-counter finalize (verbatim, proven) ----
__global__ void kC(const float* __restrict__ sp, const float* __restrict__ tx,
                   const int* __restrict__ ids, const int* __restrict__ counts,
                   const int* __restrict__ memberList,
                   const float* __restrict__ Ts, const float* __restrict__ T,
                   const float* __restrict__ lseRow, const float* __restrict__ lseCol,
                   float* scalars, float* out) {
  __shared__ float red[32];
  int tid = threadIdx.x;
  int gt = blockIdx.x * 1024 + tid;
  int g = gt >> 6, lane = gt & 63;
  int i = memberList[g];
  int s = ids[i];
  int m = counts[s];
  float4 a = *reinterpret_cast<const float4*>(sp + i * DD + lane * 4);
  float4 b = *reinterpret_cast<const float4*>(tx + i * DD + lane * 4);
  float4 c = *reinterpret_cast<const float4*>(Ts + s * DD + lane * 4);
  float4 tv = *reinterpret_cast<const float4*>(T + lane * 4);
  float dDiag = dot4(a, b);
  float dTs   = dot4(a, c);
  float dT    = dot4(a, tv);
  #pragma unroll
  for (int o = 1; o < 64; o <<= 1) {
    dDiag += __shfl_xor(dDiag, o);
    dTs   += __shfl_xor(dTs, o);
    dT    += __shfl_xor(dT, o);
  }
  if (lane == 0) {
    float term = 0.f, tri = 0.f;
    if (m >= 2) {
      term = (__logf(lseRow[g]) + __logf(lseCol[g]) - 2.f * dDiag * (1.f / TAU)) /
             (2.f * (float)m);
      float posMean = (dTs - dDiag) / fmaxf((float)(m - 1), 1.f);
      float negMean = (dT - dTs) / fmaxf((float)(BB - m), 1.f);
      if (m <= BB - 1) tri = fmaxf(negMean - posMean + MARGIN, 0.f);
    }
    int wv = tid >> 6;
    red[wv] = term;
    red[16 + wv] = tri;
  }
  __syncthreads();
  if (tid == 0) {
    float infoS = 0.f, triS = 0.f;
    #pragma unroll
    for (int w = 0; w < 16; ++w) { infoS += red[w]; triS += red[16 + w]; }
    atomicAdd(&scalars[1], infoS);
    atomicAdd(&scalars[0], triS);
    __threadfence();
    unsigned prev = atomicAdd((unsigned*)&scalars[4], 1u);
    if (prev == (unsigned)(gridDim.x - 1)) {
      float fi = atomicAdd(&scalars[1], 0.f);
      float ft = atomicAdd(&scalars[0], 0.f);
      float nv = scalars[2];
      float nvi = scalars[3];
      out[0] = fi / fmaxf(nv, 1.f) + ft / fmaxf(nvi, 1.f);
    }
  }
}

extern "C" void kernel_launch(void* const* d_in, const int* in_sizes, int n_in,
                              void* d_out, int out_size, void* d_ws, size_t ws_size,
                              hipStream_t stream) {
  const float* sp = (const float*)d_in[0];
  const float* tx = (const float*)d_in[1];
  const int* ids = (const int*)d_in[2];
  float* out = (float*)d_out;

  char* ws = (char*)d_ws;
  float* scalars = (float*)(ws + WS_SCALARS);
  int* counts = (int*)(ws + WS_COUNTS);
  int* offsets = (int*)(ws + WS_OFFSETS);
  float* lseRow = (float*)(ws + WS_LSEROW);
  float* lseCol = (float*)(ws + WS_LSECOL);
  float* Ts = (float*)(ws + WS_TS);
  float* T = (float*)(ws + WS_T);
  int* memberList = (int*)(ws + WS_MEMBER);

  kA<<<33, 1024, 0, stream>>>(ids, ws);
  kB<<<1280, 256, 0, stream>>>(sp, tx, counts, offsets, memberList,
                               Ts, T, lseRow, lseCol);
  kC<<<512, 1024, 0, stream>>>(sp, tx, ids, counts, memberList, Ts, T,
                               lseRow, lseCol, scalars, out);
}